// Round 10
// baseline (528.033 us; speedup 1.0000x reference)
//
#include <hip/hip_runtime.h>
#include <math.h>

#define NT 8192
#define NO 8192
#define FIN 256
#define FOUT 64
#define SPLIT 8
#define JSP (NO/SPLIT)  // 1024 j per split
#define ROWT 64         // rows per attention block (4 waves x 16 rows)

// workspace layout (float offsets)
#define OFF_NUM ((size_t)0)                           // SPLIT*NT*FOUT
#define OFF_DEN (OFF_NUM + (size_t)SPLIT*NT*FOUT)     // SPLIT*NT
#define OFF_SO  (OFF_DEN + (size_t)SPLIT*NT)          // NO
#define OFF_ST  (OFF_SO + (size_t)NO)                 // NT
#define OFF_HOB (OFF_ST + (size_t)NT)                 // NO*FOUT bf16 (B-frag order)
// total ~= 4.6M floats ~= 18 MB of d_ws

typedef __attribute__((ext_vector_type(8))) short short8;
typedef __attribute__((ext_vector_type(4))) float float4v;

static __device__ __forceinline__ unsigned short f2bf(float x) {
  unsigned int u = __float_as_uint(x);
  unsigned int r = (u + 0x7fffu + ((u >> 16) & 1u)) >> 16;   // RNE
  return (unsigned short)r;
}
static __device__ __forceinline__ int pk2(float a, float b) {
  return (int)((unsigned int)f2bf(a) | ((unsigned int)f2bf(b) << 16));
}
static __device__ __forceinline__ float bflo(int p) {
  return __uint_as_float(((unsigned int)p) << 16);
}
static __device__ __forceinline__ float bfhi(int p) {
  return __uint_as_float(((unsigned int)p) & 0xffff0000u);
}

// K1: prep. Folds wt=W_t@a_t via block LDS (k_wvec deleted); s_t matvec;
// h_o GEMM -> hobp bf16 in B-frag order + s_o. 512 blocks x 16 rows.
__global__ void k_prep(const float* __restrict__ tin, const float* __restrict__ oin,
                       const float* __restrict__ Wt, const float* __restrict__ Wo,
                       const float* __restrict__ a, float* __restrict__ ws) {
  __shared__ float wt_l[FIN];
  int b = blockIdx.x, t = threadIdx.x;
  int wv = t >> 6, lane = t & 63;
  // --- fold wt (redundant per block; Wt is 64KB, L2-resident) ---
  {
    float s1 = 0.f;
#pragma unroll
    for (int fq = 0; fq < FOUT/4; ++fq) {
      float4 w4 = *(const float4*)(Wt + (size_t)t*FOUT + fq*4);
      float4 a4 = *(const float4*)(a + fq*4);
      s1 += w4.x*a4.x + w4.y*a4.y + w4.z*a4.z + w4.w*a4.w;
    }
    wt_l[t] = s1;
  }
  __syncthreads();
  // --- s_t: 4 rows/wave ---
  {
    float4 w = ((const float4*)wt_l)[lane];
#pragma unroll
    for (int r = 0; r < 4; ++r) {
      int row = b*16 + wv*4 + r;
      float4 v = ((const float4*)(tin + (size_t)row*FIN))[lane];
      float p = v.x*w.x + v.y*w.y + v.z*w.z + v.w*w.w;
#pragma unroll
      for (int m = 32; m >= 1; m >>= 1) p += __shfl_xor(p, m, 64);
      if (lane == 0) ws[OFF_ST + row] = p;
    }
  }
  // --- h_o: 4 rows/wave -> hobp (B-frag order) + s_o ---
  {
    unsigned short* hobp = (unsigned short*)(ws + OFF_HOB);
    int r0 = b*16 + wv*4;
    const float* ob = oin + (size_t)r0 * FIN;
    float acc[4];
#pragma unroll
    for (int r = 0; r < 4; ++r) acc[r] = 0.f;
#pragma unroll 2
    for (int k = 0; k < FIN; k += 4) {
      float w0 = Wo[(size_t)(k+0)*FOUT + lane];
      float w1 = Wo[(size_t)(k+1)*FOUT + lane];
      float w2 = Wo[(size_t)(k+2)*FOUT + lane];
      float w3 = Wo[(size_t)(k+3)*FOUT + lane];
#pragma unroll
      for (int r = 0; r < 4; ++r) {
        float4 ov = *(const float4*)(ob + (size_t)r*FIN + k);
        acc[r] = fmaf(ov.x, w0, acc[r]);
        acc[r] = fmaf(ov.y, w1, acc[r]);
        acc[r] = fmaf(ov.z, w2, acc[r]);
        acc[r] = fmaf(ov.w, w3, acc[r]);
      }
    }
    float ao = a[FOUT + lane];
    int fg = lane >> 4, n16 = lane & 15;
#pragma unroll
    for (int r = 0; r < 4; ++r) {
      int j = r0 + r;
      int jt = j >> 5, jl = j & 31;
      int ldst = (jl >> 3) * 16 + n16;       // consumer lane
      int e = jl & 7;
      hobp[(((size_t)jt*4 + fg)*64 + ldst)*8 + e] = f2bf(acc[r]);
      float p = acc[r] * ao;
#pragma unroll
      for (int m = 32; m >= 1; m >>= 1) p += __shfl_xor(p, m, 64);
      if (lane == 0) ws[OFF_SO + j] = p;
    }
  }
}

// K2: fused attention, SINGLE PASS over adj. Each wave stages its own 16
// rows x 1024 j of adj (dword/lane coalesced, ballot -> bits) into
// wave-private padded LDS (no barrier, no global mask intermediate), then
// consumes 32 MFMA tiles: A-frag built directly in target layout from LDS
// mask bits + expf(leaky(st+so)), B from hobp (coalesced), no bpermute.
__launch_bounds__(256, 4)
__global__ void k_attn(const int* __restrict__ adj, float* __restrict__ ws) {
  __shared__ unsigned int msk[4][16][33];    // wave-private, padded (33 ≡ 1 mod 32)
  const float* st = ws + OFF_ST;
  const float* so = ws + OFF_SO;
  const unsigned short* hobp = (const unsigned short*)(ws + OFF_HOB);
  float* gnum = ws + OFF_NUM;
  float* gden = ws + OFF_DEN;

  int t = threadIdx.x, b = blockIdx.x;
  int wv = t >> 6, lane = t & 63;
  int s  = b & (SPLIT - 1);
  int bi = b >> 3;                           // log2(SPLIT)
  int i0 = bi * ROWT;
  int jb = s * JSP;

  // ---- stage: ballot-pack this wave's adj rows into LDS bits ----
  {
    const int* ab = adj + (size_t)(i0 + wv*16)*NO + jb + lane;
#pragma unroll 1
    for (int row = 0; row < 16; ++row) {
      const int* ar = ab + (size_t)row*NO;
#pragma unroll 4
      for (int g = 0; g < 16; ++g) {
        int v = ar[g*64];
        unsigned long long m = __ballot(v > 0);
        if (lane == 0) {
          msk[wv][row][2*g]   = (unsigned int)m;
          msk[wv][row][2*g+1] = (unsigned int)(m >> 32);
        }
      }
    }
  }
  // no __syncthreads needed: LDS region is wave-private, DS ops in-order

  int r16 = lane & 15, kg = lane >> 4;       // A-frag target layout
  float sti = st[i0 + wv*16 + r16];
  const float* sop = so + jb + kg*8;
  const unsigned short* hpb = hobp + (size_t)(jb >> 5)*2048 + lane*8;

  float4v acc0 = (float4v)0.f, acc1 = (float4v)0.f;
  float4v acc2 = (float4v)0.f, acc3 = (float4v)0.f;
  float dsum = 0.f;

#pragma unroll 2
  for (int tt = 0; tt < JSP/32; ++tt) {
    unsigned int msh = msk[wv][r16][tt] >> (kg*8);   // conflict-free broadcast
    float4 s0 = *(const float4*)(sop + tt*32);
    float4 s1 = *(const float4*)(sop + tt*32 + 4);
    const unsigned short* hb = hpb + (size_t)tt*2048;
    short8 b0 = *(const short8*)(hb);
    short8 b1 = *(const short8*)(hb + 512);
    short8 b2 = *(const short8*)(hb + 1024);
    short8 b3 = *(const short8*)(hb + 1536);

    float x0 = sti + s0.x; x0 = fmaxf(x0, 0.2f*x0);
    float x1 = sti + s0.y; x1 = fmaxf(x1, 0.2f*x1);
    float x2 = sti + s0.z; x2 = fmaxf(x2, 0.2f*x2);
    float x3 = sti + s0.w; x3 = fmaxf(x3, 0.2f*x3);
    float x4 = sti + s1.x; x4 = fmaxf(x4, 0.2f*x4);
    float x5 = sti + s1.y; x5 = fmaxf(x5, 0.2f*x5);
    float x6 = sti + s1.z; x6 = fmaxf(x6, 0.2f*x6);
    float x7 = sti + s1.w; x7 = fmaxf(x7, 0.2f*x7);
    float w0 = (msh & 1u)   ? __expf(x0) : 0.f;
    float w1 = (msh & 2u)   ? __expf(x1) : 0.f;
    float w2 = (msh & 4u)   ? __expf(x2) : 0.f;
    float w3 = (msh & 8u)   ? __expf(x3) : 0.f;
    float w4 = (msh & 16u)  ? __expf(x4) : 0.f;
    float w5 = (msh & 32u)  ? __expf(x5) : 0.f;
    float w6 = (msh & 64u)  ? __expf(x6) : 0.f;
    float w7 = (msh & 128u) ? __expf(x7) : 0.f;

    int p0 = pk2(w0, w1);
    int p1 = pk2(w2, w3);
    int p2 = pk2(w4, w5);
    int p3 = pk2(w6, w7);
    dsum += bflo(p0) + bfhi(p0) + bflo(p1) + bfhi(p1)
          + bflo(p2) + bfhi(p2) + bflo(p3) + bfhi(p3);

    int4 ai = {p0, p1, p2, p3};              // already in A-frag layout
    short8 afrag = *(short8*)&ai;

    acc0 = __builtin_amdgcn_mfma_f32_16x16x32_bf16(afrag, b0, acc0, 0, 0, 0);
    acc1 = __builtin_amdgcn_mfma_f32_16x16x32_bf16(afrag, b1, acc1, 0, 0, 0);
    acc2 = __builtin_amdgcn_mfma_f32_16x16x32_bf16(afrag, b2, acc2, 0, 0, 0);
    acc3 = __builtin_amdgcn_mfma_f32_16x16x32_bf16(afrag, b3, acc3, 0, 0, 0);
  }

  // den: dsum is per (row r16, k-group kg) — reduce over the 4 kg
  dsum += __shfl_xor(dsum, 16, 64);
  dsum += __shfl_xor(dsum, 32, 64);
  if (lane < 16) gden[(size_t)s*NT + i0 + wv*16 + lane] = dsum;

  // num: C/D layout col=lane&15, row=(lane>>4)*4+reg
  size_t obase = ((size_t)s*NT + i0 + wv*16 + kg*4) * FOUT + r16;
#pragma unroll
  for (int r = 0; r < 4; ++r) {
    gnum[obase + (size_t)r*FOUT +  0] = acc0[r];
    gnum[obase + (size_t)r*FOUT + 16] = acc1[r];
    gnum[obase + (size_t)r*FOUT + 32] = acc2[r];
    gnum[obase + (size_t)r*FOUT + 48] = acc3[r];
  }
}

// K3: combine splits, normalize, ELU
__global__ void k_comb(const float* __restrict__ ws, float* __restrict__ out) {
  int idx = blockIdx.x * 256 + threadIdx.x;   // 0..524287
  int i = idx >> 6;
  float num = 0.f, den = 0.f;
#pragma unroll
  for (int s = 0; s < SPLIT; ++s) {
    num += ws[OFF_NUM + ((size_t)s*NT + i)*FOUT + (idx & 63)];
    den += ws[OFF_DEN + (size_t)s*NT + i];
  }
  float r = num / den;
  out[idx] = (r > 0.f) ? r : (__expf(r) - 1.f);
}

extern "C" void kernel_launch(void* const* d_in, const int* in_sizes, int n_in,
                              void* d_out, int out_size, void* d_ws, size_t ws_size,
                              hipStream_t stream) {
  const float* tin = (const float*)d_in[0];
  const float* oin = (const float*)d_in[1];
  const float* Wt  = (const float*)d_in[2];
  const float* Wo  = (const float*)d_in[3];
  const float* a   = (const float*)d_in[4];
  const int*   adj = (const int*)d_in[5];
  float* out = (float*)d_out;
  float* ws  = (float*)d_ws;

  hipLaunchKernelGGL(k_prep, dim3(NT/16),          dim3(256), 0, stream, tin, oin, Wt, Wo, a, ws);
  hipLaunchKernelGGL(k_attn, dim3(NT/ROWT*SPLIT),  dim3(256), 0, stream, adj, ws);
  hipLaunchKernelGGL(k_comb, dim3(NT*FOUT/256),    dim3(256), 0, stream, ws, out);
}